// Round 4
// baseline (248.193 us; speedup 1.0000x reference)
//
#include <hip/hip_runtime.h>
#include <math.h>

// B=4096, IN=1024, H=2048, OUT=1024
// cosmic layer == broadcast prob[r] = (1/H)*(prod_{d,k} cos(cw[d,r,k]))^2
// Network = 6 fp16-MFMA GEMMs (32x32x16) with fused bias/relu/tanh epilogues.
//
// GEMM: BM x 128 tile (BM=256 main / 128 for G5), BK=64, 512 thr
// (8 waves 4Mx2N, 64x64 each), tri-buffered LDS (144 KB), counted vmcnt
// (T4), ONE barrier per K-tile, straight-line 16 ds_read + 16 MFMA per
// tile (compiler emits counted lgkmcnt - m97 evidence), setprio (T5),
// XOR-swizzled LDS both-sides (T2, rule 21), XCD swizzle (T1).

typedef _Float16 f16;
typedef _Float16 f16x8 __attribute__((ext_vector_type(8)));
typedef _Float16 f16x4 __attribute__((ext_vector_type(4)));
typedef float f32x16 __attribute__((ext_vector_type(16)));

#define GLD16(gp, lp) __builtin_amdgcn_global_load_lds( \
    (const __attribute__((address_space(1))) unsigned int*)(gp), \
    (__attribute__((address_space(3))) unsigned int*)(lp), 16, 0, 0)

// ---------------- fp32 -> fp16 cast ----------------
__global__ void cast_f32_f16(const float* __restrict__ in, f16* __restrict__ out, int n4) {
  int i = blockIdx.x * 256 + threadIdx.x;
  if (i < n4) {
    float4 v = ((const float4*)in)[i];
    f16x4 o = { (f16)v.x, (f16)v.y, (f16)v.z, (f16)v.w };
    ((f16x4*)out)[i] = o;
  }
}

// ------- merged cast+transpose, vectorized: 32(K) x 64(N) f32 tiles -------
struct TD { const float* src; f16* dst; int K; int N; };
struct TD6 { TD d[6]; };

__global__ void cast_transpose6(TD6 a) {
  TD d = a.d[blockIdx.z];
  const int bx = blockIdx.x * 64;   // N
  const int by = blockIdx.y * 32;   // K
  if (bx >= d.N || by >= d.K) return;
  __shared__ float tile[32][68];
  const int t = threadIdx.x;
#pragma unroll
  for (int pass = 0; pass < 2; ++pass) {
    int idx = t + pass * 256;       // 0..511
    int row = idx >> 4;             // 0..31
    int c4  = (idx & 15) * 4;       // 0..60
    float4 v = *(const float4*)&d.src[(size_t)(by + row) * d.N + bx + c4];
    *(float4*)&tile[row][c4] = v;
  }
  __syncthreads();
  const int nl = t >> 2;            // 0..63
  const int k8 = (t & 3) * 8;       // 0..24
  f16x8 o;
#pragma unroll
  for (int j = 0; j < 8; ++j) o[j] = (f16)tile[k8 + j][nl];
  *(f16x8*)&d.dst[(size_t)(bx + nl) * d.K + by + k8] = o;
}

// ---------------- cosmic prob, 2-pass ----------------
__global__ void cosmic_pp(const float* __restrict__ cw, float* __restrict__ pp, int H) {
  int i = blockIdx.x * 256 + threadIdx.x;   // i = d*H + r
  if (i >= 8 * H) return;
  const float* a = cw + (size_t)i * H;      // cw[d][r][0..2]
  pp[i] = cosf(a[0]) * cosf(a[1]) * cosf(a[2]);
}
__global__ void cosmic_fin(const float* __restrict__ pp, float* __restrict__ prob, int H) {
  int r = blockIdx.x * 256 + threadIdx.x;
  if (r >= H) return;
  float p = 1.0f;
#pragma unroll
  for (int d = 0; d < 8; ++d) p *= pp[d * H + r];
  prob[r] = p * p / (float)H;
}

// ---------------- fp16 MFMA GEMM (32x32x16) ----------------
// A: (M,K) f16 row-major. BT: (N,K) f16 row-major.
// EPI 0: relu->f16  1: tanh(+prob)->f16  2: relu->f32
template <int EPI, int BM>
__global__ __launch_bounds__(512, 2)
void gemm_f16(const f16* __restrict__ A, const f16* __restrict__ BT,
              const float* __restrict__ bias, const float* __restrict__ prob,
              f16* __restrict__ Ch, float* __restrict__ Cf,
              int M, int N, int K, int GX) {
  constexpr int ASZ = BM * 64;          // f16 per A buffer
  constexpr int BSZ = 128 * 64;         // f16 per B buffer
  constexpr int MB  = BM / 128;         // 32-row frags per wave (2 or 1)
  constexpr int RA  = BM / 64;          // A stage rounds (4 or 2)
  __shared__ f16 lds[3 * (ASZ + BSZ)];
  f16* As = lds;
  f16* Bs = lds + 3 * ASZ;

  const int t = threadIdx.x;

  // XCD-aware swizzle (nwg % 8 == 0 for all our grids)
  const int nwg = gridDim.x;
  const int bid = blockIdx.x;
  const int swz = (bid & 7) * (nwg >> 3) + (bid >> 3);
  const int bx = swz % GX;
  const int by = swz / GX;
  const int m0 = by * BM;
  const int n0 = bx * 128;

  // staging: LDS dest linear; XOR swizzle (chunk ^= row&7) pre-applied to
  // the GLOBAL source (rule 21).
  auto stage_all = [&](int kt, int buf) {
    const int k0 = kt << 6;
#pragma unroll
    for (int q = 0; q < RA; ++q) {
      int F = q * 4096 + t * 8;
      int r = F >> 6, c = (F >> 3) & 7;
      GLD16(A + (size_t)(m0 + r) * K + k0 + ((c ^ (r & 7)) << 3), As + buf * ASZ + F);
    }
#pragma unroll
    for (int q = 0; q < 2; ++q) {
      int F = q * 4096 + t * 8;
      int r = F >> 6, c = (F >> 3) & 7;
      GLD16(BT + (size_t)(n0 + r) * K + k0 + ((c ^ (r & 7)) << 3), Bs + buf * BSZ + F);
    }
  };

  const int wave = t >> 6, lane = t & 63;
  const int wr = wave >> 1, wc = wave & 1;  // 4M x 2N waves
  const int rc = lane & 31, hi = lane >> 5;

  f32x16 acc[MB][2] = {};

  const int nt = K >> 6;
  stage_all(0, 0);
  stage_all(1, 1);
  int cur = 0;
  for (int kt = 0; kt < nt; ++kt) {
    // own tile-kt loads retired; tiles kt+1(,kt+2) stay in flight
    if (kt + 1 < nt) {
      if (BM == 256) asm volatile("s_waitcnt vmcnt(6)" ::: "memory");
      else           asm volatile("s_waitcnt vmcnt(4)" ::: "memory");
    } else {
      asm volatile("s_waitcnt vmcnt(0)" ::: "memory");
    }
    __builtin_amdgcn_s_barrier();
    if (kt + 2 < nt) {
      int sb = cur + 2; if (sb >= 3) sb -= 3;
      stage_all(kt + 2, sb);              // issue prefetch first (longest latency)
    }

    const f16* Ab = As + cur * ASZ;
    const f16* Bb = Bs + cur * BSZ;
    // all 16 fragment loads up front: compiler pipelines with counted lgkmcnt
    f16x8 a[4][MB], b[4][2];
#pragma unroll
    for (int p = 0; p < 4; ++p) {
      const int cc = p * 2 + hi;          // 16B chunk index
#pragma unroll
      for (int mb = 0; mb < MB; ++mb) {
        int row = wr * (BM / 4) + mb * 32 + rc;
        a[p][mb] = *(const f16x8*)&Ab[row * 64 + ((cc ^ (row & 7)) << 3)];
      }
#pragma unroll
      for (int nb = 0; nb < 2; ++nb) {
        int row = wc * 64 + nb * 32 + rc;
        b[p][nb] = *(const f16x8*)&Bb[row * 64 + ((cc ^ (row & 7)) << 3)];
      }
    }
    __builtin_amdgcn_s_setprio(1);
#pragma unroll
    for (int p = 0; p < 4; ++p)
#pragma unroll
      for (int mb = 0; mb < MB; ++mb)
#pragma unroll
        for (int nb = 0; nb < 2; ++nb)
          acc[mb][nb] = __builtin_amdgcn_mfma_f32_32x32x16_f16(a[p][mb], b[p][nb], acc[mb][nb], 0, 0, 0);
    __builtin_amdgcn_s_setprio(0);
    cur = (cur + 1 == 3) ? 0 : cur + 1;
  }

  // epilogue: 32x32 C/D layout col=lane&31, row=(r&3)+8*(r>>2)+4*(lane>>5)
#pragma unroll
  for (int nb = 0; nb < 2; ++nb) {
    const int col = n0 + wc * 64 + nb * 32 + rc;
    float bn = bias[col];
    if (EPI == 1) bn += prob[col];
#pragma unroll
    for (int mb = 0; mb < MB; ++mb) {
      const int rbase = m0 + wr * (BM / 4) + mb * 32 + 4 * hi;
#pragma unroll
      for (int r = 0; r < 16; ++r) {
        const int row = rbase + (r & 3) + 8 * (r >> 2);
        float v = acc[mb][nb][r] + bn;
        if (EPI == 1) v = tanhf(v);
        else v = fmaxf(v, 0.0f);
        if (EPI == 2) Cf[(size_t)row * N + col] = v;
        else Ch[(size_t)row * N + col] = (f16)v;
      }
    }
  }
}

extern "C" void kernel_launch(void* const* d_in, const int* in_sizes, int n_in,
                              void* d_out, int out_size, void* d_ws, size_t ws_size,
                              hipStream_t stream) {
  const float* x   = (const float*)d_in[0];
  const float* W0  = (const float*)d_in[1];
  const float* b0  = (const float*)d_in[2];
  const float* W1  = (const float*)d_in[3];
  const float* b1  = (const float*)d_in[4];
  const float* cw1 = (const float*)d_in[5];
  const float* KW1 = (const float*)d_in[7];
  const float* Kb1 = (const float*)d_in[8];
  const float* W2  = (const float*)d_in[9];
  const float* b2  = (const float*)d_in[10];
  const float* cw2 = (const float*)d_in[11];
  const float* KW2 = (const float*)d_in[13];
  const float* Kb2 = (const float*)d_in[14];
  const float* W3  = (const float*)d_in[15];
  const float* b3  = (const float*)d_in[16];

  const int B = 4096, IN = 1024, H = 2048, OUT = 1024;

  char* ws = (char*)d_ws;
  size_t off = 0;
  auto alloc = [&](size_t bytes) {
    char* p = ws + off;
    off = (off + bytes + 255) & ~(size_t)255;
    return p;
  };
  f16* xh    = (f16*)alloc((size_t)B * IN * 2);
  f16* W0T   = (f16*)alloc((size_t)H * IN * 2);
  f16* W1T   = (f16*)alloc((size_t)H * H * 2);
  f16* KW1T  = (f16*)alloc((size_t)H * H * 2);
  f16* W2T   = (f16*)alloc((size_t)H * H * 2);
  f16* KW2T  = (f16*)alloc((size_t)H * H * 2);
  f16* W3T   = (f16*)alloc((size_t)OUT * H * 2);
  f16* hA    = (f16*)alloc((size_t)B * H * 2);
  f16* hB    = (f16*)alloc((size_t)B * H * 2);
  float* p1  = (float*)alloc((size_t)H * 4);
  float* p2  = (float*)alloc((size_t)H * 4);
  float* pp  = (float*)alloc((size_t)8 * H * 4);
  (void)ws_size;

  cast_f32_f16<<<(B * IN / 4 + 255) / 256, 256, 0, stream>>>(x, xh, B * IN / 4);

  TD6 td;
  td.d[0] = { W0,  W0T,  IN, H };
  td.d[1] = { W1,  W1T,  H,  H };
  td.d[2] = { KW1, KW1T, H,  H };
  td.d[3] = { W2,  W2T,  H,  H };
  td.d[4] = { KW2, KW2T, H,  H };
  td.d[5] = { W3,  W3T,  H,  OUT };
  cast_transpose6<<<dim3(H / 64, H / 32, 6), 256, 0, stream>>>(td);

  cosmic_pp<<<(8 * H + 255) / 256, 256, 0, stream>>>(cw1, pp, H);
  cosmic_fin<<<(H + 255) / 256, 256, 0, stream>>>(pp, p1, H);
  cosmic_pp<<<(8 * H + 255) / 256, 256, 0, stream>>>(cw2, pp, H);
  cosmic_fin<<<(H + 255) / 256, 256, 0, stream>>>(pp, p2, H);

  // G0-G4: BM=256 (grid 256). G5: BM=128 (grid 256).
  {
    int gx = H / 128, gy = B / 256;
    dim3 g(gx * gy);
    gemm_f16<0, 256><<<g, 512, 0, stream>>>(xh, W0T, b0,  nullptr, hA, nullptr, B, H, IN, gx);
    gemm_f16<0, 256><<<g, 512, 0, stream>>>(hA, W1T, b1,  nullptr, hB, nullptr, B, H, H,  gx);
    gemm_f16<1, 256><<<g, 512, 0, stream>>>(hB, KW1T, Kb1, p1,     hA, nullptr, B, H, H,  gx);
    gemm_f16<0, 256><<<g, 512, 0, stream>>>(hA, W2T, b2,  nullptr, hB, nullptr, B, H, H,  gx);
    gemm_f16<1, 256><<<g, 512, 0, stream>>>(hB, KW2T, Kb2, p2,     hA, nullptr, B, H, H,  gx);
  }
  {
    int gx = OUT / 128, gy = B / 128;
    dim3 g(gx * gy);
    gemm_f16<2, 128><<<g, 512, 0, stream>>>(hA, W3T, b3, nullptr, nullptr, (float*)d_out, B, OUT, H, gx);
  }
}